// Round 1
// baseline (2308.256 us; speedup 1.0000x reference)
//
#include <hip/hip_runtime.h>
#include <hip/hip_bf16.h>
#include <math.h>

#define NN   16384
#define EE   65536
#define DD   512
#define HH   4
#define FINN 7

// ---------------- float4 helpers ----------------
__device__ inline float4 f4zero() { return make_float4(0.f, 0.f, 0.f, 0.f); }
__device__ inline float4 f4add(float4 a, float4 b) {
  return make_float4(a.x + b.x, a.y + b.y, a.z + b.z, a.w + b.w);
}
__device__ inline float4 f4axpy(float s, float4 a, float4 acc) {
  acc.x = fmaf(s, a.x, acc.x); acc.y = fmaf(s, a.y, acc.y);
  acc.z = fmaf(s, a.z, acc.z); acc.w = fmaf(s, a.w, acc.w);
  return acc;
}
__device__ inline float wave_reduce_sum(float v) {
  #pragma unroll
  for (int off = 32; off > 0; off >>= 1) v += __shfl_down(v, off, 64);
  return v;
}
__device__ inline float wave_allreduce_sum(float v) {
  #pragma unroll
  for (int off = 32; off > 0; off >>= 1) v += __shfl_xor(v, off, 64);
  return v;
}

// ---------------- CSR build ----------------
__global__ void k_count(const int* __restrict__ dst, int* __restrict__ cnt) {
  int e = blockIdx.x * 256 + threadIdx.x;
  if (e < EE) atomicAdd(&cnt[dst[e]], 1);
}

__global__ void k_scan(const int* __restrict__ cnt, int* __restrict__ offs) {
  __shared__ int sums[256];
  int t = threadIdx.x;
  const int chunk = NN / 256;  // 64
  int base = t * chunk;
  int s = 0;
  for (int i = 0; i < chunk; ++i) s += cnt[base + i];
  sums[t] = s;
  __syncthreads();
  for (int off = 1; off < 256; off <<= 1) {
    int v = (t >= off) ? sums[t - off] : 0;
    __syncthreads();
    sums[t] += v;
    __syncthreads();
  }
  int run = (t == 0) ? 0 : sums[t - 1];
  for (int i = 0; i < chunk; ++i) {
    offs[base + i] = run;
    run += cnt[base + i];
  }
  if (t == 255) offs[NN] = run;
}

__global__ void k_fill(const int* __restrict__ dst, const int* __restrict__ offs,
                       int* __restrict__ cursor, int* __restrict__ eids) {
  int e = blockIdx.x * 256 + threadIdx.x;
  if (e >= EE) return;
  int d = dst[e];
  int p = offs[d] + atomicAdd(&cursor[d], 1);
  eids[p] = e;
}

// ---------------- edge_attr mean ----------------
__global__ void k_edge_mean(const float* __restrict__ eattr, float* __restrict__ macc) {
  int tid = blockIdx.x * blockDim.x + threadIdx.x;
  int stride = gridDim.x * blockDim.x;
  float4 a = f4zero();
  for (int e = tid; e < EE; e += stride) {
    float4 v = ((const float4*)eattr)[e];
    a.x += v.x; a.y += v.y; a.z += v.z; a.w += v.w;
  }
  a.x = wave_reduce_sum(a.x); a.y = wave_reduce_sum(a.y);
  a.z = wave_reduce_sum(a.z); a.w = wave_reduce_sum(a.w);
  if ((threadIdx.x & 63) == 0) {
    atomicAdd(&macc[0], a.x); atomicAdd(&macc[1], a.y);
    atomicAdd(&macc[2], a.z); atomicAdd(&macc[3], a.w);
  }
}

// ---------------- input projection: h = relu(x @ Wproj + b) ----------------
__global__ void k_proj(const float* __restrict__ x, const float* __restrict__ W,
                       const float* __restrict__ b, float* __restrict__ h) {
  int gid = blockIdx.x * 256 + threadIdx.x;
  if (gid >= NN * DD) return;
  int n = gid >> 9, d = gid & 511;
  const float* xr = x + n * FINN;
  float acc = b[d];
  #pragma unroll
  for (int k = 0; k < FINN; ++k) acc = fmaf(xr[k], W[k * DD + d], acc);
  h[gid] = fmaxf(acc, 0.f);
}

// ---------------- GINE aggregate: g[n] = h[n] + sum_e relu(h[src]+lin_e(attr)) ----------------
__global__ void k_gine_agg(const float* __restrict__ h, const int* __restrict__ src,
                           const float* __restrict__ eattr,
                           const float* __restrict__ geW, const float* __restrict__ geb,
                           const int* __restrict__ offs, const int* __restrict__ eids,
                           float* __restrict__ g) {
  int wave = (blockIdx.x * blockDim.x + threadIdx.x) >> 6;
  int lane = threadIdx.x & 63;
  if (wave >= NN) return;
  int n = wave;
  const float4* geW4 = (const float4*)geW;  // [4][128]
  const float4* geb4 = (const float4*)geb;  // [128]
  float4 w[2][4], bb[2];
  #pragma unroll
  for (int b = 0; b < 2; ++b) {
    int c4 = lane + b * 64;
    bb[b] = geb4[c4];
    #pragma unroll
    for (int k = 0; k < 4; ++k) w[b][k] = geW4[k * 128 + c4];
  }
  float4 acc[2] = {f4zero(), f4zero()};
  int beg = offs[n], end = offs[n + 1];
  for (int p = beg; p < end; ++p) {
    int e = eids[p];
    int s = src[e];
    float4 ea = ((const float4*)eattr)[e];
    const float4* hs = (const float4*)(h + (size_t)s * DD);
    #pragma unroll
    for (int b = 0; b < 2; ++b) {
      int c4 = lane + b * 64;
      float4 ev = bb[b];
      ev = f4axpy(ea.x, w[b][0], ev);
      ev = f4axpy(ea.y, w[b][1], ev);
      ev = f4axpy(ea.z, w[b][2], ev);
      ev = f4axpy(ea.w, w[b][3], ev);
      float4 hv = hs[c4];
      acc[b].x += fmaxf(hv.x + ev.x, 0.f);
      acc[b].y += fmaxf(hv.y + ev.y, 0.f);
      acc[b].z += fmaxf(hv.z + ev.z, 0.f);
      acc[b].w += fmaxf(hv.w + ev.w, 0.f);
    }
  }
  const float4* hn = (const float4*)(h + (size_t)n * DD);
  float4* gn = (float4*)(g + (size_t)n * DD);
  #pragma unroll
  for (int b = 0; b < 2; ++b) {
    int c4 = lane + b * 64;
    gn[c4] = f4add(hn[c4], acc[b]);
  }
}

// ---------------- generic f32 GEMM: C = act(A @ W + bias) ----------------
// A: M x K (row-major, lda=K), W: K x Nc slice with row stride ldw, C: M x Nc.
__global__ __launch_bounds__(256) void k_sgemm(
    const float* __restrict__ A, const float* __restrict__ W,
    const float* __restrict__ bias, float* __restrict__ C,
    int M, int Nc, int K, int ldw, int act) {
  __shared__ float As[8][128];
  __shared__ float Bs[8][128];
  const int tid = threadIdx.x;
  const int tx = tid & 15, ty = tid >> 4;
  const int row0 = blockIdx.y * 128, col0 = blockIdx.x * 128;
  float acc[8][8];
  #pragma unroll
  for (int i = 0; i < 8; ++i)
    #pragma unroll
    for (int j = 0; j < 8; ++j) acc[i][j] = 0.f;
  const int arow = tid >> 1;
  const int acol = (tid & 1) * 4;
  const int brow = tid >> 5;
  const int bcol = (tid & 31) * 4;
  const float* Abase = A + (size_t)(row0 + arow) * K + acol;
  const float* Wbase = W + (size_t)brow * ldw + col0 + bcol;
  for (int k0 = 0; k0 < K; k0 += 8) {
    float4 av = *(const float4*)(Abase + k0);
    float4 bv = *(const float4*)(Wbase + (size_t)k0 * ldw);
    As[acol + 0][arow] = av.x;
    As[acol + 1][arow] = av.y;
    As[acol + 2][arow] = av.z;
    As[acol + 3][arow] = av.w;
    *(float4*)&Bs[brow][bcol] = bv;
    __syncthreads();
    #pragma unroll
    for (int kk = 0; kk < 8; ++kk) {
      float a[8], b[8];
      #pragma unroll
      for (int i = 0; i < 8; ++i) a[i] = As[kk][ty * 8 + i];
      #pragma unroll
      for (int j = 0; j < 8; ++j) b[j] = Bs[kk][tx * 8 + j];
      #pragma unroll
      for (int i = 0; i < 8; ++i)
        #pragma unroll
        for (int j = 0; j < 8; ++j) acc[i][j] = fmaf(a[i], b[j], acc[i][j]);
    }
    __syncthreads();
  }
  #pragma unroll
  for (int i = 0; i < 8; ++i) {
    int r = row0 + ty * 8 + i;
    #pragma unroll
    for (int j = 0; j < 8; ++j) {
      int c = col0 + tx * 8 + j;
      float v = acc[i][j];
      if (bias) v += bias[c];
      if (act) v = fmaxf(v, 0.f);
      C[(size_t)r * Nc + c] = v;
    }
  }
}

// ---------------- fused LayerNorm: out = LN(relu(g [+ bias]) + res) ----------------
__global__ void k_ln(const float* __restrict__ g, const float* __restrict__ bias,
                     const float* __restrict__ res, const float* __restrict__ gamma,
                     const float* __restrict__ beta, float* __restrict__ out) {
  int wave = (blockIdx.x * blockDim.x + threadIdx.x) >> 6;
  int lane = threadIdx.x & 63;
  if (wave >= NN) return;
  int n = wave;
  const float4* g4 = (const float4*)(g + (size_t)n * DD);
  const float4* r4 = (const float4*)(res + (size_t)n * DD);
  float4 v[2];
  float s = 0.f, sq = 0.f;
  #pragma unroll
  for (int b = 0; b < 2; ++b) {
    int c4 = lane + b * 64;
    float4 gv = g4[c4];
    if (bias) {
      float4 bv = ((const float4*)bias)[c4];
      gv = f4add(gv, bv);
    }
    gv.x = fmaxf(gv.x, 0.f); gv.y = fmaxf(gv.y, 0.f);
    gv.z = fmaxf(gv.z, 0.f); gv.w = fmaxf(gv.w, 0.f);
    float4 rv = r4[c4];
    v[b] = f4add(gv, rv);
    s  += v[b].x + v[b].y + v[b].z + v[b].w;
    sq += v[b].x * v[b].x + v[b].y * v[b].y + v[b].z * v[b].z + v[b].w * v[b].w;
  }
  s = wave_allreduce_sum(s);
  sq = wave_allreduce_sum(sq);
  float mu = s * (1.f / DD);
  float var = sq * (1.f / DD) - mu * mu;
  float rstd = rsqrtf(var + 1e-5f);
  float4* o4 = (float4*)(out + (size_t)n * DD);
  #pragma unroll
  for (int b = 0; b < 2; ++b) {
    int c4 = lane + b * 64;
    float4 gm = ((const float4*)gamma)[c4];
    float4 bt = ((const float4*)beta)[c4];
    float4 o;
    o.x = fmaf((v[b].x - mu) * rstd, gm.x, bt.x);
    o.y = fmaf((v[b].y - mu) * rstd, gm.y, bt.y);
    o.z = fmaf((v[b].z - mu) * rstd, gm.z, bt.z);
    o.w = fmaf((v[b].w - mu) * rstd, gm.w, bt.w);
    o4[c4] = o;
  }
}

// ---------------- GATv2 logits (one wave per edge, one head) ----------------
__global__ void k_gat_logits(const float* __restrict__ xl, const float* __restrict__ xr,
                             const int* __restrict__ src, const int* __restrict__ dst,
                             const float* __restrict__ eattr, const float* __restrict__ macc,
                             const float* __restrict__ geW /*4x2048*/,
                             const float* __restrict__ att /*4x512*/,
                             int head, float* __restrict__ logits) {
  int wave = (blockIdx.x * blockDim.x + threadIdx.x) >> 6;
  int lane = threadIdx.x & 63;
  const int E2 = EE + NN;
  if (wave >= E2) return;
  int s, d;
  float4 ea;
  if (wave < EE) {
    s = src[wave]; d = dst[wave];
    ea = ((const float4*)eattr)[wave];
  } else {
    s = d = wave - EE;
    const float invE = 1.f / EE;
    ea = make_float4(macc[0] * invE, macc[1] * invE, macc[2] * invE, macc[3] * invE);
  }
  const float4* xls = (const float4*)(xl + (size_t)s * DD);
  const float4* xrd = (const float4*)(xr + (size_t)d * DD);
  const float4* geW4 = (const float4*)geW;          // row stride 512 float4
  const float4* att4 = (const float4*)(att + head * DD);
  float acc = 0.f;
  #pragma unroll
  for (int b = 0; b < 2; ++b) {
    int c4 = lane + b * 64;
    float4 z = xls[c4];
    float4 r = xrd[c4];
    float4 w0 = geW4[0 * 512 + head * 128 + c4];
    float4 w1 = geW4[1 * 512 + head * 128 + c4];
    float4 w2 = geW4[2 * 512 + head * 128 + c4];
    float4 w3 = geW4[3 * 512 + head * 128 + c4];
    z.x += r.x + ea.x * w0.x + ea.y * w1.x + ea.z * w2.x + ea.w * w3.x;
    z.y += r.y + ea.x * w0.y + ea.y * w1.y + ea.z * w2.y + ea.w * w3.y;
    z.z += r.z + ea.x * w0.z + ea.y * w1.z + ea.z * w2.z + ea.w * w3.z;
    z.w += r.w + ea.x * w0.w + ea.y * w1.w + ea.z * w2.w + ea.w * w3.w;
    z.x = (z.x >= 0.f) ? z.x : 0.2f * z.x;
    z.y = (z.y >= 0.f) ? z.y : 0.2f * z.y;
    z.z = (z.z >= 0.f) ? z.z : 0.2f * z.z;
    z.w = (z.w >= 0.f) ? z.w : 0.2f * z.w;
    float4 a = att4[c4];
    acc += z.x * a.x + z.y * a.y + z.z * a.z + z.w * a.w;
  }
  acc = wave_reduce_sum(acc);
  if (lane == 0) logits[wave] = acc;
}

// ---------------- GATv2 per-node softmax + aggregate (wave per node) ----------------
__global__ void k_gat_node(const float* __restrict__ xl, const int* __restrict__ src,
                           const int* __restrict__ offs, const int* __restrict__ eids,
                           const float* __restrict__ logits, float* __restrict__ gout,
                           int head) {
  int wave = (blockIdx.x * blockDim.x + threadIdx.x) >> 6;
  int lane = threadIdx.x & 63;
  if (wave >= NN) return;
  int n = wave;
  int beg = offs[n], end = offs[n + 1];
  float lself = logits[EE + n];
  float m = lself;
  for (int p = beg; p < end; ++p) m = fmaxf(m, logits[eids[p]]);
  float ssum = expf(lself - m);
  for (int p = beg; p < end; ++p) ssum += expf(logits[eids[p]] - m);
  float inv = 0.25f / (ssum + 1e-16f);  // fold the head-mean 1/4 in here
  float4 acc[2];
  {
    float wgt = expf(lself - m) * inv;
    const float4* xs = (const float4*)(xl + (size_t)n * DD);
    acc[0] = f4axpy(wgt, xs[lane], f4zero());
    acc[1] = f4axpy(wgt, xs[lane + 64], f4zero());
  }
  for (int p = beg; p < end; ++p) {
    int e = eids[p];
    float wgt = expf(logits[e] - m) * inv;
    const float4* xs = (const float4*)(xl + (size_t)src[e] * DD);
    acc[0] = f4axpy(wgt, xs[lane], acc[0]);
    acc[1] = f4axpy(wgt, xs[lane + 64], acc[1]);
  }
  float4* gn = (float4*)(gout + (size_t)n * DD);
  if (head == 0) {
    gn[lane] = acc[0];
    gn[lane + 64] = acc[1];
  } else {
    gn[lane] = f4add(gn[lane], acc[0]);
    gn[lane + 64] = f4add(gn[lane + 64], acc[1]);
  }
}

// ---------------- GCN helpers ----------------
__global__ void k_dinv(const int* __restrict__ cnt, float* __restrict__ dinv) {
  int n = blockIdx.x * 256 + threadIdx.x;
  if (n < NN) dinv[n] = rsqrtf((float)cnt[n] + 1.0f);
}

__global__ void k_gcn_node(const float* __restrict__ hw, const int* __restrict__ src,
                           const int* __restrict__ offs, const int* __restrict__ eids,
                           const float* __restrict__ dinv, float* __restrict__ gout) {
  int wave = (blockIdx.x * blockDim.x + threadIdx.x) >> 6;
  int lane = threadIdx.x & 63;
  if (wave >= NN) return;
  int n = wave;
  float dn = dinv[n];
  const float4* hn = (const float4*)(hw + (size_t)n * DD);
  float wself = dn * dn;
  float4 acc0 = f4axpy(wself, hn[lane], f4zero());
  float4 acc1 = f4axpy(wself, hn[lane + 64], f4zero());
  int beg = offs[n], end = offs[n + 1];
  for (int p = beg; p < end; ++p) {
    int e = eids[p];
    int s = src[e];
    float wgt = dinv[s] * dn;
    const float4* hs = (const float4*)(hw + (size_t)s * DD);
    acc0 = f4axpy(wgt, hs[lane], acc0);
    acc1 = f4axpy(wgt, hs[lane + 64], acc1);
  }
  float4* gn = (float4*)(gout + (size_t)n * DD);
  gn[lane] = acc0;
  gn[lane + 64] = acc1;
}

// ---------------- host-side launcher ----------------
static void launch_sgemm(const float* A, const float* W, const float* bias, float* C,
                         int M, int Nc, int K, int ldw, int act, hipStream_t stream) {
  dim3 grid(Nc / 128, M / 128);
  k_sgemm<<<grid, 256, 0, stream>>>(A, W, bias, C, M, Nc, K, ldw, act);
}

extern "C" void kernel_launch(void* const* d_in, const int* in_sizes, int n_in,
                              void* d_out, int out_size, void* d_ws, size_t ws_size,
                              hipStream_t stream) {
  const float* x       = (const float*)d_in[0];
  const int*   eidx    = (const int*)d_in[1];
  const float* eattr   = (const float*)d_in[2];
  const float* Wproj   = (const float*)d_in[3];
  const float* bproj   = (const float*)d_in[4];
  const float* geW     = (const float*)d_in[5];
  const float* geb     = (const float*)d_in[6];
  const float* gW1     = (const float*)d_in[7];
  const float* gb1     = (const float*)d_in[8];
  const float* gW2     = (const float*)d_in[9];
  const float* gb2     = (const float*)d_in[10];
  const float* gatWl   = (const float*)d_in[11];
  const float* gatbl   = (const float*)d_in[12];
  const float* gatWr   = (const float*)d_in[13];
  const float* gatbr   = (const float*)d_in[14];
  const float* gateW   = (const float*)d_in[15];
  const float* gatatt  = (const float*)d_in[16];
  const float* gatbias = (const float*)d_in[17];
  const float* gcn1W   = (const float*)d_in[18];
  const float* gcn1b   = (const float*)d_in[19];
  const float* gcn2W   = (const float*)d_in[20];
  const float* gcn2b   = (const float*)d_in[21];
  const float* lgamma  = (const float*)d_in[22];
  const float* lbeta   = (const float*)d_in[23];
  const int* srcArr = eidx;
  const int* dstArr = eidx + EE;

  // ---- workspace carving (~135 MB) ----
  float* A       = (float*)d_ws;                 // NN*DD
  float* B       = A + (size_t)NN * DD;          // NN*DD
  float* Cbuf    = B + (size_t)NN * DD;          // NN*1024
  float* logitsE = Cbuf + (size_t)NN * 1024;     // EE+NN
  float* macc    = logitsE + (EE + NN);          // 4
  float* dinv    = macc + 4;                     // NN
  int*   cnt     = (int*)(dinv + NN);            // NN
  int*   offs    = cnt + NN;                     // NN+1
  int*   cursor  = offs + NN + 1;                // NN
  int*   eids    = cursor + NN;                  // EE

  hipMemsetAsync(cnt, 0, NN * sizeof(int), stream);
  hipMemsetAsync(cursor, 0, NN * sizeof(int), stream);
  hipMemsetAsync(macc, 0, 4 * sizeof(float), stream);

  // CSR by destination (real edges); self-loops handled analytically.
  k_count<<<EE / 256, 256, 0, stream>>>(dstArr, cnt);
  k_scan<<<1, 256, 0, stream>>>(cnt, offs);
  k_fill<<<EE / 256, 256, 0, stream>>>(dstArr, offs, cursor, eids);
  k_edge_mean<<<64, 256, 0, stream>>>(eattr, macc);

  // input projection
  k_proj<<<NN * DD / 256, 256, 0, stream>>>(x, Wproj, bproj, A);

  // ---- layer 0: GINEConv + MLP + LN ----
  k_gine_agg<<<NN / 4, 256, 0, stream>>>(A, srcArr, eattr, geW, geb, offs, eids, B);
  launch_sgemm(B, gW1, gb1, Cbuf, NN, 1024, 512, 1024, 1, stream);    // relu(g@W1+b1)
  launch_sgemm(Cbuf, gW2, gb2, B, NN, 512, 1024, 512, 0, stream);     // @W2+b2
  k_ln<<<NN / 4, 256, 0, stream>>>(B, nullptr, A, lgamma, lbeta, A);

  // ---- layer 1: GATv2 (per-head to keep workspace small) ----
  float* X1 = Cbuf;
  float* X2 = Cbuf + (size_t)NN * DD;
  for (int head = 0; head < HH; ++head) {
    launch_sgemm(A, gatWl + head * DD, gatbl + head * DD, X1, NN, 512, 512, 2048, 0, stream);
    launch_sgemm(A, gatWr + head * DD, gatbr + head * DD, X2, NN, 512, 512, 2048, 0, stream);
    k_gat_logits<<<(EE + NN) / 4, 256, 0, stream>>>(X1, X2, srcArr, dstArr, eattr, macc,
                                                    gateW, gatatt, head, logitsE);
    k_gat_node<<<NN / 4, 256, 0, stream>>>(X1, srcArr, offs, eids, logitsE, B, head);
  }
  k_ln<<<NN / 4, 256, 0, stream>>>(B, gatbias, A, lgamma + DD, lbeta + DD, A);

  // ---- layers 2,3: GCN ----
  k_dinv<<<NN / 256, 256, 0, stream>>>(cnt, dinv);
  launch_sgemm(A, gcn1W, nullptr, Cbuf, NN, 512, 512, 512, 0, stream);
  k_gcn_node<<<NN / 4, 256, 0, stream>>>(Cbuf, srcArr, offs, eids, dinv, B);
  k_ln<<<NN / 4, 256, 0, stream>>>(B, gcn1b, A, lgamma + 2 * DD, lbeta + 2 * DD, A);

  launch_sgemm(A, gcn2W, nullptr, Cbuf, NN, 512, 512, 512, 0, stream);
  k_gcn_node<<<NN / 4, 256, 0, stream>>>(Cbuf, srcArr, offs, eids, dinv, B);
  k_ln<<<NN / 4, 256, 0, stream>>>(B, gcn2b, A, lgamma + 3 * DD, lbeta + 3 * DD,
                                   (float*)d_out);
}

// Round 2
// 973.947 us; speedup vs baseline: 2.3700x; 2.3700x over previous
//
#include <hip/hip_runtime.h>
#include <hip/hip_bf16.h>
#include <math.h>

#define NN   16384
#define EE   65536
#define DD   512
#define HH   4
#define FINN 7

typedef __attribute__((ext_vector_type(4))) float  floatx4;
typedef __attribute__((ext_vector_type(8))) short  shortx8;
typedef __attribute__((ext_vector_type(8))) unsigned short ushortx8;

// ---------------- helpers ----------------
__device__ inline float bf2f(unsigned short u) {
  return __uint_as_float(((unsigned)u) << 16);
}
__device__ inline unsigned short f2bf(float f) {
  unsigned u = __float_as_uint(f);
  unsigned r = (u + 0x7fffu + ((u >> 16) & 1u)) >> 16;
  return (unsigned short)r;
}
__device__ inline float wave_reduce_sum(float v) {
  #pragma unroll
  for (int off = 32; off > 0; off >>= 1) v += __shfl_down(v, off, 64);
  return v;
}
__device__ inline float wave_allreduce_sum(float v) {
  #pragma unroll
  for (int off = 32; off > 0; off >>= 1) v += __shfl_xor(v, off, 64);
  return v;
}
__device__ inline void async16(const unsigned short* g, unsigned short* l) {
  __builtin_amdgcn_global_load_lds(
      (const __attribute__((address_space(1))) void*)g,
      (__attribute__((address_space(3))) void*)l, 16, 0, 0);
}

// ---------------- CSR build ----------------
__global__ void k_count(const int* __restrict__ dst, int* __restrict__ cnt) {
  int e = blockIdx.x * 256 + threadIdx.x;
  if (e < EE) atomicAdd(&cnt[dst[e]], 1);
}

__global__ void k_scan(const int* __restrict__ cnt, int* __restrict__ offs) {
  __shared__ int sums[256];
  int t = threadIdx.x;
  const int chunk = NN / 256;
  int base = t * chunk;
  int s = 0;
  for (int i = 0; i < chunk; ++i) s += cnt[base + i];
  sums[t] = s;
  __syncthreads();
  for (int off = 1; off < 256; off <<= 1) {
    int v = (t >= off) ? sums[t - off] : 0;
    __syncthreads();
    sums[t] += v;
    __syncthreads();
  }
  int run = (t == 0) ? 0 : sums[t - 1];
  for (int i = 0; i < chunk; ++i) {
    offs[base + i] = run;
    run += cnt[base + i];
  }
  if (t == 255) offs[NN] = run;
}

__global__ void k_fill(const int* __restrict__ dst, const int* __restrict__ offs,
                       int* __restrict__ cursor, int* __restrict__ eids) {
  int e = blockIdx.x * 256 + threadIdx.x;
  if (e >= EE) return;
  int d = dst[e];
  int p = offs[d] + atomicAdd(&cursor[d], 1);
  eids[p] = e;
}

// ---------------- edge_attr mean ----------------
__global__ void k_edge_mean(const float* __restrict__ eattr, float* __restrict__ macc) {
  int tid = blockIdx.x * blockDim.x + threadIdx.x;
  int stride = gridDim.x * blockDim.x;
  float ax = 0.f, ay = 0.f, az = 0.f, aw = 0.f;
  for (int e = tid; e < EE; e += stride) {
    float4 v = ((const float4*)eattr)[e];
    ax += v.x; ay += v.y; az += v.z; aw += v.w;
  }
  ax = wave_reduce_sum(ax); ay = wave_reduce_sum(ay);
  az = wave_reduce_sum(az); aw = wave_reduce_sum(aw);
  if ((threadIdx.x & 63) == 0) {
    atomicAdd(&macc[0], ax); atomicAdd(&macc[1], ay);
    atomicAdd(&macc[2], az); atomicAdd(&macc[3], aw);
  }
}

// ---------------- weight transpose+cast: W[K][N] f32 -> Wt[N][K] bf16 ----------------
__global__ void k_transcast(const float* __restrict__ W, unsigned short* __restrict__ Wt,
                            int K, int N) {
  __shared__ float tile[32][33];
  int bx = blockIdx.x;  // n-tile
  int by = blockIdx.y;  // k-tile
  int tx = threadIdx.x & 31, ty = threadIdx.x >> 5;  // 32 x 8
  #pragma unroll
  for (int i = 0; i < 32; i += 8)
    tile[ty + i][tx] = W[(size_t)(by * 32 + ty + i) * N + bx * 32 + tx];
  __syncthreads();
  #pragma unroll
  for (int i = 0; i < 32; i += 8)
    Wt[(size_t)(bx * 32 + ty + i) * K + by * 32 + tx] = f2bf(tile[tx][ty + i]);
}

// ---------------- input projection: h = relu(x @ Wproj + b), f32 + bf16 out --------
__global__ void k_proj(const float* __restrict__ x, const float* __restrict__ W,
                       const float* __restrict__ b, float* __restrict__ h,
                       unsigned short* __restrict__ hbf) {
  int gid = blockIdx.x * 256 + threadIdx.x;
  if (gid >= NN * DD) return;
  int n = gid >> 9, d = gid & 511;
  const float* xr = x + n * FINN;
  float acc = b[d];
  #pragma unroll
  for (int k = 0; k < FINN; ++k) acc = fmaf(xr[k], W[k * DD + d], acc);
  acc = fmaxf(acc, 0.f);
  h[gid] = acc;
  hbf[gid] = f2bf(acc);
}

// ---------------- bf16 MFMA GEMM: C = act(A @ Bt^T + bias) ----------------
// A: M x K bf16 row-major.  Bt: N x K bf16 row-major (i.e. B transposed).
// Cout: M x Nc, f32 or bf16 depending on outbf.
__global__ __launch_bounds__(256) void k_bgemm(
    const unsigned short* __restrict__ A, const unsigned short* __restrict__ Bt,
    const float* __restrict__ bias, void* __restrict__ Cout,
    int M, int Nc, int K, int act, int outbf) {
  __shared__ unsigned short As[128 * 64];
  __shared__ unsigned short Bs[128 * 64];
  const int tid = threadIdx.x;
  const int wv = tid >> 6;
  const int lane = tid & 63;
  const int row0 = blockIdx.y * 128;
  const int col0 = blockIdx.x * 128;
  const int wrow = (wv & 1) * 64;
  const int wcol = (wv >> 1) * 64;

  floatx4 acc[4][4];
  #pragma unroll
  for (int r = 0; r < 4; ++r)
    #pragma unroll
    for (int c = 0; c < 4; ++c)
      #pragma unroll
      for (int q = 0; q < 4; ++q) acc[r][c][q] = 0.f;

  const unsigned short* Ab = A + (size_t)row0 * K;
  const unsigned short* Bb = Bt + (size_t)col0 * K;
  const int lrow = lane >> 3;          // 0..7
  const int lk = (lane & 7) * 8;       // k chunk within 64

  for (int k0 = 0; k0 < K; k0 += 64) {
    #pragma unroll
    for (int i = 0; i < 4; ++i) {
      int seg = i * 4 + wv;            // 0..15, uniform per wave
      int r = seg * 8 + lrow;          // tile row 0..127
      async16(Ab + (size_t)r * K + k0 + lk, &As[seg * 512]);
      async16(Bb + (size_t)r * K + k0 + lk, &Bs[seg * 512]);
    }
    __syncthreads();
    #pragma unroll
    for (int s = 0; s < 2; ++s) {
      shortx8 af[4], bfr[4];
      #pragma unroll
      for (int r = 0; r < 4; ++r)
        af[r] = *(const shortx8*)&As[(wrow + r * 16 + (lane & 15)) * 64 + s * 32 + (lane >> 4) * 8];
      #pragma unroll
      for (int c = 0; c < 4; ++c)
        bfr[c] = *(const shortx8*)&Bs[(wcol + c * 16 + (lane & 15)) * 64 + s * 32 + (lane >> 4) * 8];
      #pragma unroll
      for (int r = 0; r < 4; ++r)
        #pragma unroll
        for (int c = 0; c < 4; ++c)
          acc[r][c] = __builtin_amdgcn_mfma_f32_16x16x32_bf16(af[r], bfr[c], acc[r][c], 0, 0, 0);
    }
    __syncthreads();
  }

  #pragma unroll
  for (int r = 0; r < 4; ++r) {
    int rowb = row0 + wrow + r * 16 + (lane >> 4) * 4;
    #pragma unroll
    for (int c = 0; c < 4; ++c) {
      int col = col0 + wcol + c * 16 + (lane & 15);
      float bv = bias ? bias[col] : 0.f;
      #pragma unroll
      for (int q = 0; q < 4; ++q) {
        float v = acc[r][c][q] + bv;
        if (act) v = fmaxf(v, 0.f);
        if (outbf)
          ((unsigned short*)Cout)[(size_t)(rowb + q) * Nc + col] = f2bf(v);
        else
          ((float*)Cout)[(size_t)(rowb + q) * Nc + col] = v;
      }
    }
  }
}

// ---------------- GINE aggregate (bf16 gather): out = bf16(h[n] + sum relu(h_s+ev)) --
__global__ void k_gine_agg(const float* __restrict__ hf, const unsigned short* __restrict__ hbf,
                           const int* __restrict__ src, const float* __restrict__ eattr,
                           const float* __restrict__ geW, const float* __restrict__ geb,
                           const int* __restrict__ offs, const int* __restrict__ eids,
                           unsigned short* __restrict__ gbf) {
  int wave = (blockIdx.x * blockDim.x + threadIdx.x) >> 6;
  int lane = threadIdx.x & 63;
  if (wave >= NN) return;
  int n = wave;
  int cbase = lane * 8;
  float w[4][8], bb[8];
  #pragma unroll
  for (int j = 0; j < 8; ++j) bb[j] = geb[cbase + j];
  #pragma unroll
  for (int k = 0; k < 4; ++k)
    #pragma unroll
    for (int j = 0; j < 8; ++j) w[k][j] = geW[k * DD + cbase + j];
  float acc[8] = {0.f};
  int beg = offs[n], end = offs[n + 1];
  for (int p = beg; p < end; ++p) {
    int e = eids[p];
    int s = src[e];
    float4 ea = ((const float4*)eattr)[e];
    ushortx8 hv = *(const ushortx8*)(hbf + (size_t)s * DD + cbase);
    #pragma unroll
    for (int j = 0; j < 8; ++j) {
      float ev = bb[j];
      ev = fmaf(ea.x, w[0][j], ev);
      ev = fmaf(ea.y, w[1][j], ev);
      ev = fmaf(ea.z, w[2][j], ev);
      ev = fmaf(ea.w, w[3][j], ev);
      acc[j] += fmaxf(bf2f(hv[j]) + ev, 0.f);
    }
  }
  const float* hn = hf + (size_t)n * DD + cbase;
  ushortx8 o;
  #pragma unroll
  for (int j = 0; j < 8; ++j) o[j] = f2bf(hn[j] + acc[j]);
  *(ushortx8*)(gbf + (size_t)n * DD + cbase) = o;
}

// ---------------- fused LayerNorm: out = LN(relu(g [+ bias]) + res), f32 + opt bf16 --
__global__ void k_ln(const float* __restrict__ g, const float* __restrict__ bias,
                     const float* __restrict__ res, const float* __restrict__ gamma,
                     const float* __restrict__ beta, float* __restrict__ out,
                     unsigned short* __restrict__ obf) {
  int wave = (blockIdx.x * blockDim.x + threadIdx.x) >> 6;
  int lane = threadIdx.x & 63;
  if (wave >= NN) return;
  int n = wave;
  int cbase = lane * 8;
  const float* gr = g + (size_t)n * DD + cbase;
  const float* rr = res + (size_t)n * DD + cbase;
  float v[8];
  float s = 0.f, sq = 0.f;
  #pragma unroll
  for (int j = 0; j < 8; ++j) {
    float gv = gr[j];
    if (bias) gv += bias[cbase + j];
    gv = fmaxf(gv, 0.f);
    float t = gv + rr[j];
    v[j] = t;
    s += t; sq += t * t;
  }
  s = wave_allreduce_sum(s);
  sq = wave_allreduce_sum(sq);
  float mu = s * (1.f / DD);
  float var = sq * (1.f / DD) - mu * mu;
  float rstd = rsqrtf(var + 1e-5f);
  float* orow = out + (size_t)n * DD + cbase;
  ushortx8 ob;
  #pragma unroll
  for (int j = 0; j < 8; ++j) {
    float o = fmaf((v[j] - mu) * rstd, gamma[cbase + j], beta[cbase + j]);
    orow[j] = o;
    ob[j] = f2bf(o);
  }
  if (obf) *(ushortx8*)(obf + (size_t)n * DD + cbase) = ob;
}

// ---------------- GATv2 logits (8 edges per wave, one head) ----------------
#define ECH 8
__global__ void k_gat_logits(const unsigned short* __restrict__ xl,
                             const unsigned short* __restrict__ xr,
                             const int* __restrict__ src, const int* __restrict__ dst,
                             const float* __restrict__ eattr, const float* __restrict__ macc,
                             const float* __restrict__ geW /*4x2048*/,
                             const float* __restrict__ att /*4x512*/,
                             int head, float* __restrict__ logits) {
  int wave = (blockIdx.x * blockDim.x + threadIdx.x) >> 6;
  int lane = threadIdx.x & 63;
  const int E2 = EE + NN;
  int e0 = wave * ECH;
  if (e0 >= E2) return;
  int cbase = lane * 8;
  float w[4][8], at[8];
  #pragma unroll
  for (int k = 0; k < 4; ++k)
    #pragma unroll
    for (int j = 0; j < 8; ++j) w[k][j] = geW[k * (HH * DD) + head * DD + cbase + j];
  #pragma unroll
  for (int j = 0; j < 8; ++j) at[j] = att[head * DD + cbase + j];
  const float invE = 1.f / EE;
  float mx = macc[0] * invE, my = macc[1] * invE, mz = macc[2] * invE, mw = macc[3] * invE;
  int e1 = e0 + ECH < E2 ? e0 + ECH : E2;
  for (int e = e0; e < e1; ++e) {
    int s, d;
    float eax, eay, eaz, eaw;
    if (e < EE) {
      s = src[e]; d = dst[e];
      float4 ea = ((const float4*)eattr)[e];
      eax = ea.x; eay = ea.y; eaz = ea.z; eaw = ea.w;
    } else {
      s = d = e - EE;
      eax = mx; eay = my; eaz = mz; eaw = mw;
    }
    ushortx8 lv = *(const ushortx8*)(xl + (size_t)s * DD + cbase);
    ushortx8 rv = *(const ushortx8*)(xr + (size_t)d * DD + cbase);
    float acc = 0.f;
    #pragma unroll
    for (int j = 0; j < 8; ++j) {
      float z = bf2f(lv[j]) + bf2f(rv[j]);
      z = fmaf(eax, w[0][j], z);
      z = fmaf(eay, w[1][j], z);
      z = fmaf(eaz, w[2][j], z);
      z = fmaf(eaw, w[3][j], z);
      z = (z >= 0.f) ? z : 0.2f * z;
      acc = fmaf(z, at[j], acc);
    }
    acc = wave_reduce_sum(acc);
    if (lane == 0) logits[e] = acc;
  }
}

// ---------------- GATv2 per-node softmax + aggregate (wave per node) ----------------
__global__ void k_gat_node(const unsigned short* __restrict__ xl, const int* __restrict__ src,
                           const int* __restrict__ offs, const int* __restrict__ eids,
                           const float* __restrict__ logits, float* __restrict__ gout,
                           int head) {
  int wave = (blockIdx.x * blockDim.x + threadIdx.x) >> 6;
  int lane = threadIdx.x & 63;
  if (wave >= NN) return;
  int n = wave;
  int cbase = lane * 8;
  int beg = offs[n], end = offs[n + 1];
  float lself = logits[EE + n];
  float m = lself;
  for (int p = beg; p < end; ++p) m = fmaxf(m, logits[eids[p]]);
  float ssum = __expf(lself - m);
  for (int p = beg; p < end; ++p) ssum += __expf(logits[eids[p]] - m);
  float inv = 0.25f / (ssum + 1e-16f);  // fold head-mean 1/4
  float acc[8];
  {
    float wgt = __expf(lself - m) * inv;
    ushortx8 xs = *(const ushortx8*)(xl + (size_t)n * DD + cbase);
    #pragma unroll
    for (int j = 0; j < 8; ++j) acc[j] = wgt * bf2f(xs[j]);
  }
  for (int p = beg; p < end; ++p) {
    int e = eids[p];
    float wgt = __expf(logits[e] - m) * inv;
    ushortx8 xs = *(const ushortx8*)(xl + (size_t)src[e] * DD + cbase);
    #pragma unroll
    for (int j = 0; j < 8; ++j) acc[j] = fmaf(wgt, bf2f(xs[j]), acc[j]);
  }
  float* gn = gout + (size_t)n * DD + cbase;
  if (head == 0) {
    #pragma unroll
    for (int j = 0; j < 8; ++j) gn[j] = acc[j];
  } else {
    #pragma unroll
    for (int j = 0; j < 8; ++j) gn[j] += acc[j];
  }
}

// ---------------- GCN ----------------
__global__ void k_dinv(const int* __restrict__ cnt, float* __restrict__ dinv) {
  int n = blockIdx.x * 256 + threadIdx.x;
  if (n < NN) dinv[n] = rsqrtf((float)cnt[n] + 1.0f);
}

__global__ void k_gcn_node(const unsigned short* __restrict__ hw, const int* __restrict__ src,
                           const int* __restrict__ offs, const int* __restrict__ eids,
                           const float* __restrict__ dinv, float* __restrict__ gout) {
  int wave = (blockIdx.x * blockDim.x + threadIdx.x) >> 6;
  int lane = threadIdx.x & 63;
  if (wave >= NN) return;
  int n = wave;
  int cbase = lane * 8;
  float dn = dinv[n];
  float acc[8];
  {
    float wself = dn * dn;
    ushortx8 hv = *(const ushortx8*)(hw + (size_t)n * DD + cbase);
    #pragma unroll
    for (int j = 0; j < 8; ++j) acc[j] = wself * bf2f(hv[j]);
  }
  int beg = offs[n], end = offs[n + 1];
  for (int p = beg; p < end; ++p) {
    int e = eids[p];
    int s = src[e];
    float wgt = dinv[s] * dn;
    ushortx8 hv = *(const ushortx8*)(hw + (size_t)s * DD + cbase);
    #pragma unroll
    for (int j = 0; j < 8; ++j) acc[j] = fmaf(wgt, bf2f(hv[j]), acc[j]);
  }
  float* gn = gout + (size_t)n * DD + cbase;
  #pragma unroll
  for (int j = 0; j < 8; ++j) gn[j] = acc[j];
}

// ---------------- host-side launcher ----------------
static void launch_bgemm(const unsigned short* A, const unsigned short* Bt,
                         const float* bias, void* C, int M, int Nc, int K,
                         int act, int outbf, hipStream_t stream) {
  dim3 grid(Nc / 128, M / 128);
  k_bgemm<<<grid, 256, 0, stream>>>(A, Bt, bias, C, M, Nc, K, act, outbf);
}

extern "C" void kernel_launch(void* const* d_in, const int* in_sizes, int n_in,
                              void* d_out, int out_size, void* d_ws, size_t ws_size,
                              hipStream_t stream) {
  const float* x       = (const float*)d_in[0];
  const int*   eidx    = (const int*)d_in[1];
  const float* eattr   = (const float*)d_in[2];
  const float* Wproj   = (const float*)d_in[3];
  const float* bproj   = (const float*)d_in[4];
  const float* geW     = (const float*)d_in[5];
  const float* geb     = (const float*)d_in[6];
  const float* gW1     = (const float*)d_in[7];
  const float* gb1     = (const float*)d_in[8];
  const float* gW2     = (const float*)d_in[9];
  const float* gb2     = (const float*)d_in[10];
  const float* gatWl   = (const float*)d_in[11];
  const float* gatbl   = (const float*)d_in[12];
  const float* gatWr   = (const float*)d_in[13];
  const float* gatbr   = (const float*)d_in[14];
  const float* gateW   = (const float*)d_in[15];
  const float* gatatt  = (const float*)d_in[16];
  const float* gatbias = (const float*)d_in[17];
  const float* gcn1W   = (const float*)d_in[18];
  const float* gcn1b   = (const float*)d_in[19];
  const float* gcn2W   = (const float*)d_in[20];
  const float* gcn2b   = (const float*)d_in[21];
  const float* lgamma  = (const float*)d_in[22];
  const float* lbeta   = (const float*)d_in[23];
  const int* srcArr = eidx;
  const int* dstArr = eidx + EE;

  // ---- workspace carving (~136 MB) ----
  char* p = (char*)d_ws;
  float* A        = (float*)p;          p += (size_t)NN * DD * 4;        // 32MB  f32 residual/LN-out
  float* B        = (float*)p;          p += (size_t)NN * DD * 4;        // 32MB  f32 pre-LN accum
  unsigned short* Xbf = (unsigned short*)p; p += (size_t)NN * DD * 2;    // 16MB  bf16 of h / LN-out
  unsigned short* Ybf = (unsigned short*)p; p += (size_t)NN * 1024 * 2;  // 32MB  bf16 (MLP mid / xl / hw)
  unsigned short* Zbf = (unsigned short*)p; p += (size_t)NN * DD * 2;    // 16MB  bf16 (gine g / xr)
  unsigned short* w1t = (unsigned short*)p; p += (size_t)1024 * 512 * 2;
  unsigned short* w2t = (unsigned short*)p; p += (size_t)512 * 1024 * 2;
  unsigned short* wlt = (unsigned short*)p; p += (size_t)2048 * 512 * 2;
  unsigned short* wrt = (unsigned short*)p; p += (size_t)2048 * 512 * 2;
  unsigned short* g1t = (unsigned short*)p; p += (size_t)512 * 512 * 2;
  unsigned short* g2t = (unsigned short*)p; p += (size_t)512 * 512 * 2;
  float* logitsE  = (float*)p;          p += (size_t)(EE + NN) * 4;
  float* macc     = (float*)p;          p += 4 * 4;
  float* dinv     = (float*)p;          p += (size_t)NN * 4;
  int*   cnt      = (int*)p;            p += (size_t)NN * 4;
  int*   offs     = (int*)p;            p += (size_t)(NN + 1) * 4 + 12;
  int*   cursor   = (int*)p;            p += (size_t)NN * 4;
  int*   eids     = (int*)p;            p += (size_t)EE * 4;

  hipMemsetAsync(cnt, 0, NN * sizeof(int), stream);
  hipMemsetAsync(cursor, 0, NN * sizeof(int), stream);
  hipMemsetAsync(macc, 0, 4 * sizeof(float), stream);

  // CSR by destination; self-loops handled analytically.
  k_count<<<EE / 256, 256, 0, stream>>>(dstArr, cnt);
  k_scan<<<1, 256, 0, stream>>>(cnt, offs);
  k_fill<<<EE / 256, 256, 0, stream>>>(dstArr, offs, cursor, eids);
  k_edge_mean<<<64, 256, 0, stream>>>(eattr, macc);

  // weight transpose+cast (f32 KxN -> bf16 NxK)
  {
    dim3 b(256);
    k_transcast<<<dim3(1024 / 32, 512 / 32), b, 0, stream>>>(gW1, w1t, 512, 1024);
    k_transcast<<<dim3(512 / 32, 1024 / 32), b, 0, stream>>>(gW2, w2t, 1024, 512);
    k_transcast<<<dim3(2048 / 32, 512 / 32), b, 0, stream>>>(gatWl, wlt, 512, 2048);
    k_transcast<<<dim3(2048 / 32, 512 / 32), b, 0, stream>>>(gatWr, wrt, 512, 2048);
    k_transcast<<<dim3(512 / 32, 512 / 32), b, 0, stream>>>(gcn1W, g1t, 512, 512);
    k_transcast<<<dim3(512 / 32, 512 / 32), b, 0, stream>>>(gcn2W, g2t, 512, 512);
  }

  // input projection (f32 + bf16)
  k_proj<<<NN * DD / 256, 256, 0, stream>>>(x, Wproj, bproj, A, Xbf);

  // ---- layer 0: GINEConv + MLP + LN ----
  k_gine_agg<<<NN / 4, 256, 0, stream>>>(A, Xbf, srcArr, eattr, geW, geb, offs, eids, Zbf);
  launch_bgemm(Zbf, w1t, gb1, Ybf, NN, 1024, 512, 1, 1, stream);   // relu(g@W1+b1) -> bf16
  launch_bgemm(Ybf, w2t, gb2, B, NN, 512, 1024, 0, 0, stream);     // @W2+b2 -> f32
  k_ln<<<NN / 4, 256, 0, stream>>>(B, nullptr, A, lgamma, lbeta, A, Xbf);

  // ---- layer 1: GATv2 (per-head) ----
  const int E2 = EE + NN;
  for (int head = 0; head < HH; ++head) {
    launch_bgemm(Xbf, wlt + (size_t)head * 512 * 512, gatbl + head * DD, Ybf,
                 NN, 512, 512, 0, 1, stream);                      // xl bf16
    launch_bgemm(Xbf, wrt + (size_t)head * 512 * 512, gatbr + head * DD, Zbf,
                 NN, 512, 512, 0, 1, stream);                      // xr bf16
    int waves = (E2 + ECH - 1) / ECH;
    k_gat_logits<<<(waves + 3) / 4, 256, 0, stream>>>(Ybf, Zbf, srcArr, dstArr, eattr,
                                                      macc, gateW, gatatt, head, logitsE);
    k_gat_node<<<NN / 4, 256, 0, stream>>>(Ybf, srcArr, offs, eids, logitsE, B, head);
  }
  k_ln<<<NN / 4, 256, 0, stream>>>(B, gatbias, A, lgamma + DD, lbeta + DD, A, Xbf);

  // ---- layers 2,3: GCN ----
  k_dinv<<<NN / 256, 256, 0, stream>>>(cnt, dinv);
  launch_bgemm(Xbf, g1t, nullptr, Ybf, NN, 512, 512, 0, 1, stream);
  k_gcn_node<<<NN / 4, 256, 0, stream>>>(Ybf, srcArr, offs, eids, dinv, B);
  k_ln<<<NN / 4, 256, 0, stream>>>(B, gcn1b, A, lgamma + 2 * DD, lbeta + 2 * DD, A, Xbf);

  launch_bgemm(Xbf, g2t, nullptr, Ybf, NN, 512, 512, 0, 1, stream);
  k_gcn_node<<<NN / 4, 256, 0, stream>>>(Ybf, srcArr, offs, eids, dinv, B);
  k_ln<<<NN / 4, 256, 0, stream>>>(B, gcn2b, A, lgamma + 3 * DD, lbeta + 3 * DD,
                                   (float*)d_out, nullptr);
}

// Round 3
// 741.867 us; speedup vs baseline: 3.1114x; 1.3128x over previous
//
#include <hip/hip_runtime.h>
#include <hip/hip_bf16.h>
#include <math.h>

#define NN   16384
#define EE   65536
#define DD   512
#define HH   4
#define FINN 7

typedef __attribute__((ext_vector_type(4))) float  floatx4;
typedef __attribute__((ext_vector_type(8))) short  shortx8;
typedef __attribute__((ext_vector_type(8))) unsigned short ushortx8;

// ---------------- helpers ----------------
__device__ inline float bf2f(unsigned short u) {
  return __uint_as_float(((unsigned)u) << 16);
}
__device__ inline unsigned short f2bf(float f) {
  unsigned u = __float_as_uint(f);
  unsigned r = (u + 0x7fffu + ((u >> 16) & 1u)) >> 16;
  return (unsigned short)r;
}
__device__ inline float wave_reduce_sum(float v) {
  #pragma unroll
  for (int off = 32; off > 0; off >>= 1) v += __shfl_down(v, off, 64);
  return v;
}
__device__ inline float wave_allreduce_sum(float v) {
  #pragma unroll
  for (int off = 32; off > 0; off >>= 1) v += __shfl_xor(v, off, 64);
  return v;
}
__device__ inline float half_allreduce_sum(float v) {  // reduce within 32-lane halves
  #pragma unroll
  for (int off = 16; off > 0; off >>= 1) v += __shfl_xor(v, off, 64);
  return v;
}
__device__ inline void async16(const unsigned short* g, unsigned short* l) {
  __builtin_amdgcn_global_load_lds(
      (const __attribute__((address_space(1))) void*)g,
      (__attribute__((address_space(3))) void*)l, 16, 0, 0);
}

// ---------------- CSR build ----------------
__global__ void k_count(const int* __restrict__ dst, int* __restrict__ cnt) {
  int e = blockIdx.x * 256 + threadIdx.x;
  if (e < EE) atomicAdd(&cnt[dst[e]], 1);
}

__global__ void k_scan(const int* __restrict__ cnt, int* __restrict__ offs) {
  __shared__ int sums[256];
  int t = threadIdx.x;
  const int chunk = NN / 256;
  int base = t * chunk;
  int s = 0;
  for (int i = 0; i < chunk; ++i) s += cnt[base + i];
  sums[t] = s;
  __syncthreads();
  for (int off = 1; off < 256; off <<= 1) {
    int v = (t >= off) ? sums[t - off] : 0;
    __syncthreads();
    sums[t] += v;
    __syncthreads();
  }
  int run = (t == 0) ? 0 : sums[t - 1];
  for (int i = 0; i < chunk; ++i) {
    offs[base + i] = run;
    run += cnt[base + i];
  }
  if (t == 255) offs[NN] = run;
}

__global__ void k_fill(const int* __restrict__ dst, const int* __restrict__ offs,
                       int* __restrict__ cursor, int* __restrict__ eids) {
  int e = blockIdx.x * 256 + threadIdx.x;
  if (e >= EE) return;
  int d = dst[e];
  int p = offs[d] + atomicAdd(&cursor[d], 1);
  eids[p] = e;
}

// ---------------- edge_attr mean ----------------
__global__ void k_edge_mean(const float* __restrict__ eattr, float* __restrict__ macc) {
  int tid = blockIdx.x * blockDim.x + threadIdx.x;
  int stride = gridDim.x * blockDim.x;
  float ax = 0.f, ay = 0.f, az = 0.f, aw = 0.f;
  for (int e = tid; e < EE; e += stride) {
    float4 v = ((const float4*)eattr)[e];
    ax += v.x; ay += v.y; az += v.z; aw += v.w;
  }
  ax = wave_reduce_sum(ax); ay = wave_reduce_sum(ay);
  az = wave_reduce_sum(az); aw = wave_reduce_sum(aw);
  if ((threadIdx.x & 63) == 0) {
    atomicAdd(&macc[0], ax); atomicAdd(&macc[1], ay);
    atomicAdd(&macc[2], az); atomicAdd(&macc[3], aw);
  }
}

// ------------- weight transpose+cast: W slice (K x N, ld) f32 -> Wt[N][K] bf16 -------
__global__ void k_transcast(const float* __restrict__ W, int ld,
                            unsigned short* __restrict__ Wt, int K, int N) {
  __shared__ float tile[32][33];
  int bx = blockIdx.x;  // n-tile
  int by = blockIdx.y;  // k-tile
  int tx = threadIdx.x & 31, ty = threadIdx.x >> 5;  // 32 x 8
  #pragma unroll
  for (int i = 0; i < 32; i += 8)
    tile[ty + i][tx] = W[(size_t)(by * 32 + ty + i) * ld + bx * 32 + tx];
  __syncthreads();
  #pragma unroll
  for (int i = 0; i < 32; i += 8)
    Wt[(size_t)(bx * 32 + ty + i) * K + by * 32 + tx] = f2bf(tile[tx][ty + i]);
}

// ------------- combined GAT bias: bc_b[c] = c<1024 ? bl[b*1024+c] : br[b*1024+c-1024]
__global__ void k_bcomb(const float* __restrict__ bl, const float* __restrict__ br,
                        float* __restrict__ bc0, float* __restrict__ bc1) {
  int i = blockIdx.x * 256 + threadIdx.x;
  if (i >= 4096) return;
  int b = i >> 11, c = i & 2047;
  float v = (c < 1024) ? bl[b * 1024 + c] : br[b * 1024 + c - 1024];
  (b ? bc1 : bc0)[c] = v;
}

// ---------------- input projection: hbf = bf16(relu(x @ Wproj + b)) ----------------
__global__ void k_proj(const float* __restrict__ x, const float* __restrict__ W,
                       const float* __restrict__ b, unsigned short* __restrict__ hbf) {
  int gid = blockIdx.x * 256 + threadIdx.x;
  if (gid >= NN * DD) return;
  int n = gid >> 9, d = gid & 511;
  const float* xr = x + n * FINN;
  float acc = b[d];
  #pragma unroll
  for (int k = 0; k < FINN; ++k) acc = fmaf(xr[k], W[k * DD + d], acc);
  hbf[gid] = f2bf(fmaxf(acc, 0.f));
}

// ---------------- bf16 MFMA GEMM: C = act(A @ Bt^T + bias) ----------------
__global__ __launch_bounds__(256) void k_bgemm(
    const unsigned short* __restrict__ A, const unsigned short* __restrict__ Bt,
    const float* __restrict__ bias, void* __restrict__ Cout,
    int M, int Nc, int K, int act, int outbf) {
  __shared__ unsigned short As[128 * 64];
  __shared__ unsigned short Bs[128 * 64];
  const int tid = threadIdx.x;
  const int wv = tid >> 6;
  const int lane = tid & 63;
  const int row0 = blockIdx.y * 128;
  const int col0 = blockIdx.x * 128;
  const int wrow = (wv & 1) * 64;
  const int wcol = (wv >> 1) * 64;

  floatx4 acc[4][4];
  #pragma unroll
  for (int r = 0; r < 4; ++r)
    #pragma unroll
    for (int c = 0; c < 4; ++c)
      #pragma unroll
      for (int q = 0; q < 4; ++q) acc[r][c][q] = 0.f;

  const unsigned short* Ab = A + (size_t)row0 * K;
  const unsigned short* Bb = Bt + (size_t)col0 * K;
  const int lrow = lane >> 3;
  const int lk = (lane & 7) * 8;

  for (int k0 = 0; k0 < K; k0 += 64) {
    #pragma unroll
    for (int i = 0; i < 4; ++i) {
      int seg = i * 4 + wv;
      int r = seg * 8 + lrow;
      async16(Ab + (size_t)r * K + k0 + lk, &As[seg * 512]);
      async16(Bb + (size_t)r * K + k0 + lk, &Bs[seg * 512]);
    }
    __syncthreads();
    #pragma unroll
    for (int s = 0; s < 2; ++s) {
      shortx8 af[4], bfr[4];
      #pragma unroll
      for (int r = 0; r < 4; ++r)
        af[r] = *(const shortx8*)&As[(wrow + r * 16 + (lane & 15)) * 64 + s * 32 + (lane >> 4) * 8];
      #pragma unroll
      for (int c = 0; c < 4; ++c)
        bfr[c] = *(const shortx8*)&Bs[(wcol + c * 16 + (lane & 15)) * 64 + s * 32 + (lane >> 4) * 8];
      #pragma unroll
      for (int r = 0; r < 4; ++r)
        #pragma unroll
        for (int c = 0; c < 4; ++c)
          acc[r][c] = __builtin_amdgcn_mfma_f32_16x16x32_bf16(af[r], bfr[c], acc[r][c], 0, 0, 0);
    }
    __syncthreads();
  }

  #pragma unroll
  for (int r = 0; r < 4; ++r) {
    int rowb = row0 + wrow + r * 16 + (lane >> 4) * 4;
    #pragma unroll
    for (int c = 0; c < 4; ++c) {
      int col = col0 + wcol + c * 16 + (lane & 15);
      float bv = bias ? bias[col] : 0.f;
      #pragma unroll
      for (int q = 0; q < 4; ++q) {
        float v = acc[r][c][q] + bv;
        if (act) v = fmaxf(v, 0.f);
        if (outbf)
          ((unsigned short*)Cout)[(size_t)(rowb + q) * Nc + col] = f2bf(v);
        else
          ((float*)Cout)[(size_t)(rowb + q) * Nc + col] = v;
      }
    }
  }
}

// ------------- GINE aggregate: gbf = bf16(h[n] + sum relu(h_s + lin_e)) -------------
__global__ void k_gine_agg(const unsigned short* __restrict__ hbf,
                           const int* __restrict__ src, const float* __restrict__ eattr,
                           const float* __restrict__ geW, const float* __restrict__ geb,
                           const int* __restrict__ offs, const int* __restrict__ eids,
                           unsigned short* __restrict__ gbf) {
  int wave = (blockIdx.x * blockDim.x + threadIdx.x) >> 6;
  int lane = threadIdx.x & 63;
  if (wave >= NN) return;
  int n = wave;
  int cbase = lane * 8;
  float w[4][8], bb[8];
  #pragma unroll
  for (int j = 0; j < 8; ++j) bb[j] = geb[cbase + j];
  #pragma unroll
  for (int k = 0; k < 4; ++k)
    #pragma unroll
    for (int j = 0; j < 8; ++j) w[k][j] = geW[k * DD + cbase + j];
  float acc[8] = {0.f};
  int beg = offs[n], end = offs[n + 1];
  for (int p = beg; p < end; ++p) {
    int e = eids[p];
    int s = src[e];
    float4 ea = ((const float4*)eattr)[e];
    ushortx8 hv = *(const ushortx8*)(hbf + (size_t)s * DD + cbase);
    #pragma unroll
    for (int j = 0; j < 8; ++j) {
      float ev = bb[j];
      ev = fmaf(ea.x, w[0][j], ev);
      ev = fmaf(ea.y, w[1][j], ev);
      ev = fmaf(ea.z, w[2][j], ev);
      ev = fmaf(ea.w, w[3][j], ev);
      acc[j] += fmaxf(bf2f(hv[j]) + ev, 0.f);
    }
  }
  ushortx8 hn = *(const ushortx8*)(hbf + (size_t)n * DD + cbase);
  ushortx8 o;
  #pragma unroll
  for (int j = 0; j < 8; ++j) o[j] = f2bf(bf2f(hn[j]) + acc[j]);
  *(ushortx8*)(gbf + (size_t)n * DD + cbase) = o;
}

// -------- layer-0 LayerNorm: Xbf = bf16(LN(relu(g) + res)), g f32, res/out bf16 -----
__global__ void k_ln0(const float* __restrict__ g, const unsigned short* __restrict__ res,
                      const float* __restrict__ gamma, const float* __restrict__ beta,
                      unsigned short* __restrict__ obf) {
  int wave = (blockIdx.x * blockDim.x + threadIdx.x) >> 6;
  int lane = threadIdx.x & 63;
  if (wave >= NN) return;
  int n = wave;
  int cbase = lane * 8;
  const float4* g4 = (const float4*)(g + (size_t)n * DD + cbase);
  ushortx8 rv = *(const ushortx8*)(res + (size_t)n * DD + cbase);
  float4 ga = g4[0], gb = g4[1];
  float v[8] = {ga.x, ga.y, ga.z, ga.w, gb.x, gb.y, gb.z, gb.w};
  float s = 0.f, sq = 0.f;
  #pragma unroll
  for (int j = 0; j < 8; ++j) {
    float t = fmaxf(v[j], 0.f) + bf2f(rv[j]);
    v[j] = t;
    s += t; sq += t * t;
  }
  s = wave_allreduce_sum(s);
  sq = wave_allreduce_sum(sq);
  float mu = s * (1.f / DD);
  float var = sq * (1.f / DD) - mu * mu;
  float rstd = rsqrtf(var + 1e-5f);
  ushortx8 ob;
  #pragma unroll
  for (int j = 0; j < 8; ++j)
    ob[j] = f2bf(fmaf((v[j] - mu) * rstd, gamma[cbase + j], beta[cbase + j]));
  *(ushortx8*)(obf + (size_t)n * DD + cbase) = ob;
}

// ---------------- GATv2 logits, 2 heads per pass (half-wave per head) ---------------
#define ECH 8
__global__ void k_gat_logits2(const unsigned short* __restrict__ xlr,
                              const int* __restrict__ src, const int* __restrict__ dst,
                              const float* __restrict__ eattr, const float* __restrict__ macc,
                              const float* __restrict__ geW /*4x2048*/,
                              const float* __restrict__ att /*4x512*/,
                              int batch, float* __restrict__ logits /* [E2][2] */) {
  int wave = (blockIdx.x * blockDim.x + threadIdx.x) >> 6;
  int lane = threadIdx.x & 63;
  const int E2 = EE + NN;
  int e0 = wave * ECH;
  if (e0 >= E2) return;
  int half = lane >> 5;          // head-local 0/1
  int li = lane & 31;
  int cb = li * 16;              // col within head
  int hc = (2 * batch + half) * 512 + cb;   // col within H*C
  float w[4][16], at[16];
  #pragma unroll
  for (int k = 0; k < 4; ++k)
    #pragma unroll
    for (int j = 0; j < 16; ++j) w[k][j] = geW[k * (HH * DD) + hc + j];
  #pragma unroll
  for (int j = 0; j < 16; ++j) at[j] = att[hc + j];
  const float invE = 1.f / EE;
  float mx = macc[0] * invE, my = macc[1] * invE, mz = macc[2] * invE, mw = macc[3] * invE;
  int xloff = half * 512 + cb;
  int xroff = 1024 + half * 512 + cb;
  int e1 = e0 + ECH < E2 ? e0 + ECH : E2;
  for (int e = e0; e < e1; ++e) {
    int s, d;
    float eax, eay, eaz, eaw;
    if (e < EE) {
      s = src[e]; d = dst[e];
      float4 ea = ((const float4*)eattr)[e];
      eax = ea.x; eay = ea.y; eaz = ea.z; eaw = ea.w;
    } else {
      s = d = e - EE;
      eax = mx; eay = my; eaz = mz; eaw = mw;
    }
    const unsigned short* ls = xlr + (size_t)s * 2048 + xloff;
    const unsigned short* rs = xlr + (size_t)d * 2048 + xroff;
    ushortx8 l0 = *(const ushortx8*)ls, l1 = *(const ushortx8*)(ls + 8);
    ushortx8 r0 = *(const ushortx8*)rs, r1 = *(const ushortx8*)(rs + 8);
    float acc = 0.f;
    #pragma unroll
    for (int j = 0; j < 16; ++j) {
      float z = (j < 8 ? bf2f(l0[j]) + bf2f(r0[j]) : bf2f(l1[j - 8]) + bf2f(r1[j - 8]));
      z = fmaf(eax, w[0][j], z);
      z = fmaf(eay, w[1][j], z);
      z = fmaf(eaz, w[2][j], z);
      z = fmaf(eaw, w[3][j], z);
      z = (z >= 0.f) ? z : 0.2f * z;
      acc = fmaf(z, at[j], acc);
    }
    acc = half_allreduce_sum(acc);
    if (li == 0) logits[(size_t)e * 2 + half] = acc;
  }
}

// ------- GATv2 softmax+aggregate, 2 heads; batch1 fuses bias/relu/res/LN -----------
__global__ void k_gat_node2(const unsigned short* __restrict__ xlr,
                            const int* __restrict__ src,
                            const int* __restrict__ offs, const int* __restrict__ eids,
                            const float* __restrict__ logits, float* __restrict__ B,
                            unsigned short* __restrict__ Xbf,
                            const float* __restrict__ gbias,
                            const float* __restrict__ gamma, const float* __restrict__ beta,
                            int batch) {
  int wave = (blockIdx.x * blockDim.x + threadIdx.x) >> 6;
  int lane = threadIdx.x & 63;
  if (wave >= NN) return;
  int n = wave;
  int half = lane >> 5;
  int li = lane & 31;
  int cb = li * 16;
  int beg = offs[n], end = offs[n + 1];
  float ls0 = logits[(size_t)(EE + n) * 2];
  float ls1 = logits[(size_t)(EE + n) * 2 + 1];
  float m0 = ls0, m1 = ls1;
  for (int p = beg; p < end; ++p) {
    int e = eids[p];
    m0 = fmaxf(m0, logits[(size_t)e * 2]);
    m1 = fmaxf(m1, logits[(size_t)e * 2 + 1]);
  }
  float s0 = __expf(ls0 - m0), s1 = __expf(ls1 - m1);
  for (int p = beg; p < end; ++p) {
    int e = eids[p];
    s0 += __expf(logits[(size_t)e * 2] - m0);
    s1 += __expf(logits[(size_t)e * 2 + 1] - m1);
  }
  float inv0 = 1.f / (s0 + 1e-16f), inv1 = 1.f / (s1 + 1e-16f);
  float msel = half ? m1 : m0;
  float isel = half ? inv1 : inv0;
  int xloff = half * 512 + cb;
  float acc[16];
  {
    float lsel = half ? ls1 : ls0;
    float wgt = __expf(lsel - msel) * isel;
    const unsigned short* xs = xlr + (size_t)n * 2048 + xloff;
    ushortx8 a0 = *(const ushortx8*)xs, a1 = *(const ushortx8*)(xs + 8);
    #pragma unroll
    for (int j = 0; j < 8; ++j) { acc[j] = wgt * bf2f(a0[j]); acc[j + 8] = wgt * bf2f(a1[j]); }
  }
  for (int p = beg; p < end; ++p) {
    int e = eids[p];
    float lg = logits[(size_t)e * 2 + half];
    float wgt = __expf(lg - msel) * isel;
    const unsigned short* xs = xlr + (size_t)src[e] * 2048 + xloff;
    ushortx8 a0 = *(const ushortx8*)xs, a1 = *(const ushortx8*)(xs + 8);
    #pragma unroll
    for (int j = 0; j < 8; ++j) {
      acc[j] = fmaf(wgt, bf2f(a0[j]), acc[j]);
      acc[j + 8] = fmaf(wgt, bf2f(a1[j]), acc[j + 8]);
    }
  }
  // sum the two heads (lane L += lane L+32)
  #pragma unroll
  for (int j = 0; j < 16; ++j) acc[j] += __shfl_xor(acc[j], 32, 64);

  if (batch == 0) {
    if (half == 0) {
      float4* bp = (float4*)(B + (size_t)n * DD + cb);
      #pragma unroll
      for (int q = 0; q < 4; ++q)
        bp[q] = make_float4(acc[q * 4], acc[q * 4 + 1], acc[q * 4 + 2], acc[q * 4 + 3]);
    }
    return;
  }
  // batch 1: finish mean over 4 heads, bias, relu, +res, LN, write bf16
  float v[16];
  float s = 0.f, sq = 0.f;
  if (half == 0) {
    const float4* bp = (const float4*)(B + (size_t)n * DD + cb);
    const unsigned short* rp = Xbf + (size_t)n * DD + cb;
    ushortx8 r0 = *(const ushortx8*)rp, r1 = *(const ushortx8*)(rp + 8);
    #pragma unroll
    for (int q = 0; q < 4; ++q) {
      float4 bv = bp[q];
      float pb[4] = {bv.x, bv.y, bv.z, bv.w};
      #pragma unroll
      for (int t = 0; t < 4; ++t) {
        int j = q * 4 + t;
        float g = (pb[t] + acc[j]) * 0.25f + gbias[cb + j];
        float rr = (j < 8) ? bf2f(r0[j]) : bf2f(r1[j - 8]);
        float val = fmaxf(g, 0.f) + rr;
        v[j] = val;
        s += val; sq += val * val;
      }
    }
  }
  s = wave_allreduce_sum(s);     // upper half contributes 0
  sq = wave_allreduce_sum(sq);
  float mu = s * (1.f / DD);
  float var = sq * (1.f / DD) - mu * mu;
  float rstd = rsqrtf(var + 1e-5f);
  if (half == 0) {
    ushortx8 o0, o1;
    #pragma unroll
    for (int j = 0; j < 8; ++j) {
      o0[j] = f2bf(fmaf((v[j] - mu) * rstd, gamma[cb + j], beta[cb + j]));
      o1[j] = f2bf(fmaf((v[j + 8] - mu) * rstd, gamma[cb + j + 8], beta[cb + j + 8]));
    }
    *(ushortx8*)(Xbf + (size_t)n * DD + cb) = o0;
    *(ushortx8*)(Xbf + (size_t)n * DD + cb + 8) = o1;
  }
}

// ---------------- GCN aggregate + fused bias/relu/res/LN ----------------
__global__ void k_dinv(const int* __restrict__ cnt, float* __restrict__ dinv) {
  int n = blockIdx.x * 256 + threadIdx.x;
  if (n < NN) dinv[n] = rsqrtf((float)cnt[n] + 1.0f);
}

__global__ void k_gcn_ln(const unsigned short* __restrict__ hw, const int* __restrict__ src,
                         const int* __restrict__ offs, const int* __restrict__ eids,
                         const float* __restrict__ dinv, const float* __restrict__ bias,
                         const float* __restrict__ gamma, const float* __restrict__ beta,
                         unsigned short* __restrict__ Xbf, float* __restrict__ outf) {
  int wave = (blockIdx.x * blockDim.x + threadIdx.x) >> 6;
  int lane = threadIdx.x & 63;
  if (wave >= NN) return;
  int n = wave;
  int cbase = lane * 8;
  float dn = dinv[n];
  float acc[8];
  {
    float wself = dn * dn;
    ushortx8 hv = *(const ushortx8*)(hw + (size_t)n * DD + cbase);
    #pragma unroll
    for (int j = 0; j < 8; ++j) acc[j] = wself * bf2f(hv[j]);
  }
  int beg = offs[n], end = offs[n + 1];
  for (int p = beg; p < end; ++p) {
    int e = eids[p];
    int s = src[e];
    float wgt = dinv[s] * dn;
    ushortx8 hv = *(const ushortx8*)(hw + (size_t)s * DD + cbase);
    #pragma unroll
    for (int j = 0; j < 8; ++j) acc[j] = fmaf(wgt, bf2f(hv[j]), acc[j]);
  }
  ushortx8 rv = *(const ushortx8*)(Xbf + (size_t)n * DD + cbase);
  float v[8];
  float s = 0.f, sq = 0.f;
  #pragma unroll
  for (int j = 0; j < 8; ++j) {
    float g = acc[j] + bias[cbase + j];
    float t = fmaxf(g, 0.f) + bf2f(rv[j]);
    v[j] = t;
    s += t; sq += t * t;
  }
  s = wave_allreduce_sum(s);
  sq = wave_allreduce_sum(sq);
  float mu = s * (1.f / DD);
  float var = sq * (1.f / DD) - mu * mu;
  float rstd = rsqrtf(var + 1e-5f);
  if (outf) {
    float4* o4 = (float4*)(outf + (size_t)n * DD + cbase);
    float o[8];
    #pragma unroll
    for (int j = 0; j < 8; ++j)
      o[j] = fmaf((v[j] - mu) * rstd, gamma[cbase + j], beta[cbase + j]);
    o4[0] = make_float4(o[0], o[1], o[2], o[3]);
    o4[1] = make_float4(o[4], o[5], o[6], o[7]);
  } else {
    ushortx8 ob;
    #pragma unroll
    for (int j = 0; j < 8; ++j)
      ob[j] = f2bf(fmaf((v[j] - mu) * rstd, gamma[cbase + j], beta[cbase + j]));
    *(ushortx8*)(Xbf + (size_t)n * DD + cbase) = ob;
  }
}

// ---------------- host-side launcher ----------------
static void launch_bgemm(const unsigned short* A, const unsigned short* Bt,
                         const float* bias, void* C, int M, int Nc, int K,
                         int act, int outbf, hipStream_t stream) {
  dim3 grid(Nc / 128, M / 128);
  k_bgemm<<<grid, 256, 0, stream>>>(A, Bt, bias, C, M, Nc, K, act, outbf);
}

extern "C" void kernel_launch(void* const* d_in, const int* in_sizes, int n_in,
                              void* d_out, int out_size, void* d_ws, size_t ws_size,
                              hipStream_t stream) {
  const float* x       = (const float*)d_in[0];
  const int*   eidx    = (const int*)d_in[1];
  const float* eattr   = (const float*)d_in[2];
  const float* Wproj   = (const float*)d_in[3];
  const float* bproj   = (const float*)d_in[4];
  const float* geW     = (const float*)d_in[5];
  const float* geb     = (const float*)d_in[6];
  const float* gW1     = (const float*)d_in[7];
  const float* gb1     = (const float*)d_in[8];
  const float* gW2     = (const float*)d_in[9];
  const float* gb2     = (const float*)d_in[10];
  const float* gatWl   = (const float*)d_in[11];
  const float* gatbl   = (const float*)d_in[12];
  const float* gatWr   = (const float*)d_in[13];
  const float* gatbr   = (const float*)d_in[14];
  const float* gateW   = (const float*)d_in[15];
  const float* gatatt  = (const float*)d_in[16];
  const float* gatbias = (const float*)d_in[17];
  const float* gcn1W   = (const float*)d_in[18];
  const float* gcn1b   = (const float*)d_in[19];
  const float* gcn2W   = (const float*)d_in[20];
  const float* gcn2b   = (const float*)d_in[21];
  const float* lgamma  = (const float*)d_in[22];
  const float* lbeta   = (const float*)d_in[23];
  const int* srcArr = eidx;
  const int* dstArr = eidx + EE;

  // ---- workspace carving (~126 MB) ----
  char* p = (char*)d_ws;
  float* B            = (float*)p;          p += (size_t)NN * DD * 4;        // 32MB
  unsigned short* Xbf = (unsigned short*)p; p += (size_t)NN * DD * 2;        // 16MB
  unsigned short* U   = (unsigned short*)p; p += (size_t)NN * 2048 * 2;      // 64MB union
  unsigned short* w1t = (unsigned short*)p; p += (size_t)1024 * 512 * 2;
  unsigned short* w2t = (unsigned short*)p; p += (size_t)512 * 1024 * 2;
  unsigned short* wc0 = (unsigned short*)p; p += (size_t)2048 * 512 * 2;
  unsigned short* wc1 = (unsigned short*)p; p += (size_t)2048 * 512 * 2;
  unsigned short* g1t = (unsigned short*)p; p += (size_t)512 * 512 * 2;
  unsigned short* g2t = (unsigned short*)p; p += (size_t)512 * 512 * 2;
  float* bc0      = (float*)p;          p += 2048 * 4;
  float* bc1      = (float*)p;          p += 2048 * 4;
  float* logitsE  = (float*)p;          p += (size_t)(EE + NN) * 2 * 4;
  float* macc     = (float*)p;          p += 4 * 4;
  float* dinv     = (float*)p;          p += (size_t)NN * 4;
  int*   cnt      = (int*)p;            p += (size_t)NN * 4;
  int*   offs     = (int*)p;            p += (size_t)(NN + 1) * 4 + 12;
  int*   cursor   = (int*)p;            p += (size_t)NN * 4;
  int*   eids     = (int*)p;            p += (size_t)EE * 4;

  unsigned short* Zbf = U;                    // NN x 512 (GINE agg out)
  unsigned short* Ybf = U + (size_t)NN * 512; // NN x 1024 (MLP mid)
  unsigned short* XLR = U;                    // NN x 2048 (GAT xl|xr, 2 heads)
  unsigned short* hw  = U;                    // NN x 512 (GCN h@W)

  hipMemsetAsync(cnt, 0, NN * sizeof(int), stream);
  hipMemsetAsync(cursor, 0, NN * sizeof(int), stream);
  hipMemsetAsync(macc, 0, 4 * sizeof(float), stream);

  k_count<<<EE / 256, 256, 0, stream>>>(dstArr, cnt);
  k_scan<<<1, 256, 0, stream>>>(cnt, offs);
  k_fill<<<EE / 256, 256, 0, stream>>>(dstArr, offs, cursor, eids);
  k_edge_mean<<<64, 256, 0, stream>>>(eattr, macc);

  // weight prep
  {
    k_transcast<<<dim3(1024 / 32, 512 / 32), 256, 0, stream>>>(gW1, 1024, w1t, 512, 1024);
    k_transcast<<<dim3(512 / 32, 1024 / 32), 256, 0, stream>>>(gW2, 512, w2t, 1024, 512);
    // combined [Wl | Wr] per 2-head batch: rows 0-1023 = Wl cols, 1024-2047 = Wr cols
    k_transcast<<<dim3(1024 / 32, 512 / 32), 256, 0, stream>>>(gatWl, 2048, wc0, 512, 1024);
    k_transcast<<<dim3(1024 / 32, 512 / 32), 256, 0, stream>>>(gatWr, 2048, wc0 + (size_t)1024 * 512, 512, 1024);
    k_transcast<<<dim3(1024 / 32, 512 / 32), 256, 0, stream>>>(gatWl + 1024, 2048, wc1, 512, 1024);
    k_transcast<<<dim3(1024 / 32, 512 / 32), 256, 0, stream>>>(gatWr + 1024, 2048, wc1 + (size_t)1024 * 512, 512, 1024);
    k_transcast<<<dim3(512 / 32, 512 / 32), 256, 0, stream>>>(gcn1W, 512, g1t, 512, 512);
    k_transcast<<<dim3(512 / 32, 512 / 32), 256, 0, stream>>>(gcn2W, 512, g2t, 512, 512);
    k_bcomb<<<16, 256, 0, stream>>>(gatbl, gatbr, bc0, bc1);
  }

  // input projection (bf16 only)
  k_proj<<<NN * DD / 256, 256, 0, stream>>>(x, Wproj, bproj, Xbf);

  // ---- layer 0: GINEConv + MLP + LN ----
  k_gine_agg<<<NN / 4, 256, 0, stream>>>(Xbf, srcArr, eattr, geW, geb, offs, eids, Zbf);
  launch_bgemm(Zbf, w1t, gb1, Ybf, NN, 1024, 512, 1, 1, stream);
  launch_bgemm(Ybf, w2t, gb2, B, NN, 512, 1024, 0, 0, stream);
  k_ln0<<<NN / 4, 256, 0, stream>>>(B, Xbf, lgamma, lbeta, Xbf);

  // ---- layer 1: GATv2, two 2-head batches ----
  const int E2 = EE + NN;
  int lwaves = (E2 + ECH - 1) / ECH;
  for (int b = 0; b < 2; ++b) {
    launch_bgemm(Xbf, b ? wc1 : wc0, b ? bc1 : bc0, XLR, NN, 2048, 512, 0, 1, stream);
    k_gat_logits2<<<(lwaves + 3) / 4, 256, 0, stream>>>(XLR, srcArr, dstArr, eattr, macc,
                                                        gateW, gatatt, b, logitsE);
    k_gat_node2<<<NN / 4, 256, 0, stream>>>(XLR, srcArr, offs, eids, logitsE, B, Xbf,
                                            gatbias, lgamma + DD, lbeta + DD, b);
  }

  // ---- layers 2,3: GCN (aggregate + fused LN) ----
  k_dinv<<<NN / 256, 256, 0, stream>>>(cnt, dinv);
  launch_bgemm(Xbf, g1t, nullptr, hw, NN, 512, 512, 0, 1, stream);
  k_gcn_ln<<<NN / 4, 256, 0, stream>>>(hw, srcArr, offs, eids, dinv, gcn1b,
                                       lgamma + 2 * DD, lbeta + 2 * DD, Xbf, nullptr);
  launch_bgemm(Xbf, g2t, nullptr, hw, NN, 512, 512, 0, 1, stream);
  k_gcn_ln<<<NN / 4, 256, 0, stream>>>(hw, srcArr, offs, eids, dinv, gcn2b,
                                       lgamma + 3 * DD, lbeta + 3 * DD, Xbf, (float*)d_out);
}